// Round 17
// baseline (303.124 us; speedup 1.0000x reference)
//
#include <hip/hip_runtime.h>
#include <hip/hip_bf16.h>
#include <stdint.h>

#define SEQ 2048
#define DDIM 768
#define KF 24
#define NKV 48
#define NZC 8   // outz split-K slices (jj-chunk of 2)

typedef unsigned short ushort_t;
typedef __attribute__((ext_vector_type(8))) short short8;
typedef __attribute__((ext_vector_type(4))) float f32x4;

typedef __attribute__((address_space(3))) uint32_t lds_u32;
typedef __attribute__((address_space(1))) uint32_t glb_u32;

__device__ __forceinline__ unsigned short f2bf(float f) {
    union { float f; uint32_t u; } v; v.f = f;
    uint32_t u = v.u;
    return (unsigned short)((u + 0x7fff + ((u >> 16) & 1)) >> 16);
}

// Image layout for a [128 rows][64 k] bf16 slab (16 KB), XOR-swizzled:
//   idx(row,k) = row*64 + (((k>>3) ^ (row&7))<<3) + (k&7)

// ---------------- fused prep: pack_x (192) + pack_M (3456) + build_T (408) ----------------
__global__ void k_prep(const float* __restrict__ x, const float* __restrict__ Mp,
                       const float* __restrict__ Mm, const float* __restrict__ phi,
                       ushort_t* __restrict__ xpk, ushort_t* __restrict__ Mpk,
                       ushort_t* __restrict__ Tpk) {
    __shared__ ushort_t lt[128 * 66];
    __shared__ float phiL[256];
    int b0 = blockIdx.x;
    int tid = threadIdx.x;

    if (b0 < 192) {                       // ---- pack_x: b = tt*12 + ks
        int b = b0;
        int tt = b / 12, ks = b % 12;
        ushort_t* dst = xpk + (size_t)b * 8192;
        const float* src = x + (size_t)tt * 128 * DDIM + ks * 64;
#pragma unroll
        for (int p = 0; p < 4; ++p) {
            int s = p * 256 + tid;
            int row = s >> 3, sl = s & 7;
            const float* rp = src + (size_t)row * DDIM + sl * 8;
            float4 a = *(const float4*)rp;
            float4 c = *(const float4*)(rp + 4);
            ushort_t v[8] = {f2bf(a.x), f2bf(a.y), f2bf(a.z), f2bf(a.w),
                             f2bf(c.x), f2bf(c.y), f2bf(c.z), f2bf(c.w)};
            *(uint4*)(dst + row * 64 + ((sl ^ (row & 7)) << 3)) = *(uint4*)v;
        }
    } else if (b0 < 192 + 3456) {         // ---- pack_M: b = (kv*6 + et)*12 + ks
        int b = b0 - 192;
        int kv = b / 72; int rem = b % 72; int et = rem / 12, ks = rem % 12;
        const float* src = ((kv < KF) ? Mp + (size_t)kv * DDIM * DDIM
                                      : Mm + (size_t)(kv - KF) * DDIM * DDIM)
                           + (size_t)(ks * 64) * DDIM + et * 128;
#pragma unroll
        for (int p = 0; p < 32; ++p) {
            int lin = p * 256 + tid;
            int d = lin >> 7, e = lin & 127;
            lt[e * 66 + d] = f2bf(src[(size_t)d * DDIM + e]);
        }
        __syncthreads();
        ushort_t* dst = Mpk + (size_t)b * 8192;
#pragma unroll
        for (int p = 0; p < 4; ++p) {
            int s = p * 256 + tid; int row = s >> 3, sl = s & 7;
            ushort_t v[8];
#pragma unroll
            for (int j = 0; j < 8; ++j) v[j] = lt[row * 66 + sl * 8 + j];
            *(uint4*)(dst + row * 64 + ((sl ^ (row & 7)) << 3)) = *(uint4*)v;
        }
    } else {                              // ---- build_T (plus filters only): b = kv24*17 + slot
        int b = b0 - (192 + 3456);
        int kv = b / 17, slot = b % 17;
        int dm = slot - 1;                // lag block; dm = -1 -> all zeros
        int tau = 128 * dm - 127 + tid;
        float v = 0.f;
        if (tid < 255 && tau >= 0 && tau < SEQ)
            v = phi[(size_t)tau * KF + kv];
        phiL[tid] = v;
        __syncthreads();
        ushort_t* dst = Tpk + (size_t)b * 2 * 8192;
#pragma unroll
        for (int h = 0; h < 2; ++h) {
#pragma unroll
            for (int p = 0; p < 4; ++p) {
                int s = p * 256 + tid; int row = s >> 3, sl = s & 7;
                ushort_t v8[8];
#pragma unroll
                for (int j = 0; j < 8; ++j) {
                    int col = h * 64 + sl * 8 + j;
                    v8[j] = f2bf(phiL[row - col + 127]);
                }
                *(uint4*)(dst + h * 8192 + row * 64 + ((sl ^ (row & 7)) << 3)) = *(uint4*)v8;
            }
        }
    }
}

// ---------------- stage A (r15 exact): Apk[kv][et][tt][h][img] ----------------
// For kv >= KF (minus branch), columns t are pre-scaled by (-1)^t (D-trick).
__global__ __launch_bounds__(256, 2)
void k_gemm_A(const ushort_t* __restrict__ Mpk, const ushort_t* __restrict__ xpk,
              ushort_t* __restrict__ Apk) {
    __shared__ ushort_t smem[2][2][8192];
    int bid = blockIdx.x;
    int lid = (bid & 7) * 576 + (bid >> 3);   // bijective: XCD k owns kv in [6k, 6k+6)
    int kv = lid / 96; int rem = lid % 96; int et = rem / 16, tt = rem % 16;
    const ushort_t* Abase = Mpk + ((size_t)(kv * 6 + et) * 12) * 8192;
    const ushort_t* Bbase = xpk + (size_t)(tt * 12) * 8192;
    int tid = threadIdx.x, lane = tid & 63, wave = tid >> 6;
    int wm = wave >> 1, wn = wave & 1;

    auto stage4 = [&](const ushort_t* src, ushort_t* dst) {
        const char* s = (const char*)src + wave * 4096 + lane * 16;
        char* l = (char*)dst + wave * 4096;
#pragma unroll
        for (int p = 0; p < 4; ++p)
            __builtin_amdgcn_global_load_lds((const glb_u32*)(s + p * 1024),
                                             (lds_u32*)(l + p * 1024), 16, 0, 0);
    };

    f32x4 acc[4][4];
#pragma unroll
    for (int m = 0; m < 4; ++m)
#pragma unroll
        for (int n = 0; n < 4; ++n) acc[m][n] = (f32x4){0.f, 0.f, 0.f, 0.f};

    stage4(Abase, smem[0][0]);
    stage4(Bbase, smem[0][1]);

    for (int s = 0; s < 12; ++s) {
        int c = s & 1;
        bool more = (s + 1 < 12);
        if (more) {
            stage4(Abase + (s + 1) * 8192, smem[c ^ 1][0]);
            asm volatile("s_waitcnt vmcnt(4)" ::: "memory");
        } else {
            asm volatile("s_waitcnt vmcnt(0)" ::: "memory");
        }
        __builtin_amdgcn_s_barrier();
        __builtin_amdgcn_sched_barrier(0);

        const ushort_t* As = smem[c][0];
        const ushort_t* Bs = smem[c][1];
        short8 av[2][4], bv[2][4];
#pragma unroll
        for (int kk = 0; kk < 2; ++kk) {
            int slot = kk * 4 + (lane >> 4);
#pragma unroll
            for (int m = 0; m < 4; ++m) {
                int row = wm * 64 + m * 16 + (lane & 15);
                av[kk][m] = *(const short8*)(As + row * 64 + ((slot ^ (row & 7)) << 3));
            }
#pragma unroll
            for (int n = 0; n < 4; ++n) {
                int row = wn * 64 + n * 16 + (lane & 15);
                bv[kk][n] = *(const short8*)(Bs + row * 64 + ((slot ^ (row & 7)) << 3));
            }
        }
        if (more) stage4(Bbase + (s + 1) * 8192, smem[c ^ 1][1]);

        asm volatile("s_waitcnt lgkmcnt(0)" ::: "memory");
        __builtin_amdgcn_sched_barrier(0);

        __builtin_amdgcn_s_setprio(1);
#pragma unroll
        for (int kk = 0; kk < 2; ++kk)
#pragma unroll
            for (int m = 0; m < 4; ++m)
#pragma unroll
                for (int n = 0; n < 4; ++n)
                    acc[m][n] = __builtin_amdgcn_mfma_f32_16x16x32_bf16(av[kk][m], bv[kk][n], acc[m][n], 0, 0, 0);
        __builtin_amdgcn_s_setprio(0);
        __builtin_amdgcn_s_barrier();
    }

    // repack C tile (rows=e, cols=t); minus branch pre-scaled by (-1)^t (t parity = lane&1)
    float fs = (kv >= KF && (lane & 1)) ? -1.f : 1.f;
    ushort_t* sm = &smem[0][0][0];
#pragma unroll
    for (int m = 0; m < 4; ++m) {
        int rb = wm * 64 + m * 16 + ((lane >> 4) << 2);
#pragma unroll
        for (int n = 0; n < 4; ++n) {
            int cb = wn * 64 + n * 16 + (lane & 15);
            int h = cb >> 6, c6 = cb & 63, sl = c6 >> 3, j = c6 & 7;
#pragma unroll
            for (int r = 0; r < 4; ++r) {
                int row = rb + r;
                sm[h * 8192 + row * 64 + ((sl ^ (row & 7)) << 3) + j] = f2bf(fs * acc[m][n][r]);
            }
        }
    }
    __syncthreads();
    uint4* d4 = (uint4*)(Apk + ((size_t)((kv * 6 + et) * 16 + tt) * 2) * 8192);
    const uint4* s4 = (const uint4*)sm;
#pragma unroll
    for (int p = 0; p < 8; ++p) d4[p * 256 + tid] = s4[p * 256 + tid];
}

// ---------------- stage B v6 (r15 exact): D-trick dual-acc, (et,zc,i1) ordering ----------------
// Unit (et, zc, i1): jj in {2zc, 2zc+1}; kv24 in [0,24); sub-steps (jj, sign, h).
// sign=1 re-fetches the SAME T image (L2 hit) and accumulates into accm;
// out = accp + D*accm, D = diag((-1)^srow) -> reg-parity sign in epilogue.
__global__ __launch_bounds__(256, 2)
void k_gemm_Bv6(const ushort_t* __restrict__ Tpk, const ushort_t* __restrict__ Apk,
                float* __restrict__ outz) {
    __shared__ ushort_t smem[2][2][8192];   // [buf][0=T, 1=A]

    int bid = blockIdx.x;                    // bijective XCD swizzle: 432 = 8*54
    int lid = (bid & 7) * 54 + (bid >> 3);
    int et = lid / 72;
    int r = lid % 72;
    int zc = 0;                              // group prefix P(z) = z*(17-z)
#pragma unroll
    for (int z = 1; z < 8; ++z) if (r >= z * (17 - z)) zc = z;
    int i1 = 2 * zc + (r - zc * (17 - zc));
    int jlo = zc * 2;

    int tid = threadIdx.x, lane = tid & 63, wave = tid >> 6;
    int wm = wave >> 1, wn = wave & 1;

    f32x4 accp[4][4], accm[4][4];
#pragma unroll
    for (int m = 0; m < 4; ++m)
#pragma unroll
        for (int n = 0; n < 4; ++n) {
            accp[m][n] = (f32x4){0.f, 0.f, 0.f, 0.f};
            accm[m][n] = (f32x4){0.f, 0.f, 0.f, 0.f};
        }

    // T slot for (i1, jj): i1 - jj + 1; padded jj = i1+1 -> slot 0 = zeros
    auto timg = [&](int kv24, int jjs, int h) -> const ushort_t* {
        return Tpk + ((size_t)((kv24 * 17 + (i1 - (jlo + jjs) + 1)) * 2 + h)) * 8192;
    };
    auto aimg = [&](int kv24, int sign, int jjs, int h) -> const ushort_t* {
        return Apk + ((size_t)((((kv24 + KF * sign) * 6 + et) * 16 + (jlo + jjs)) * 2 + h)) * 8192;
    };
    auto stage4 = [&](const ushort_t* src, ushort_t* dst) {
        const char* s = (const char*)src + wave * 4096 + lane * 16;
        char* l = (char*)dst + wave * 4096;
#pragma unroll
        for (int p = 0; p < 4; ++p)
            __builtin_amdgcn_global_load_lds((const glb_u32*)(s + p * 1024),
                                             (lds_u32*)(l + p * 1024), 16, 0, 0);
    };

    // prologue: step (kv24=0, rem=0) into buf 0
    stage4(timg(0, 0, 0), smem[0][0]);
    stage4(aimg(0, 0, 0, 0), smem[0][1]);

    for (int kv24 = 0; kv24 < KF; ++kv24) {
#pragma unroll
        for (int rem = 0; rem < 8; ++rem) {           // rem = jjs*4 + sign*2 + h
            const int sign = (rem >> 1) & 1, h = rem & 1;
            const int c = h;                          // step parity == h
            const int nrem = (rem + 1) & 7;
            const int njjs = nrem >> 2, nsign = (nrem >> 1) & 1, nh = nrem & 1;
            int nkv = kv24 + (rem == 7);
            bool more = (nkv < KF);

            if (more) {
                stage4(timg(nkv, njjs, nh), smem[c ^ 1][0]);
                asm volatile("s_waitcnt vmcnt(4)" ::: "memory");   // this step's 8 landed
            } else {
                asm volatile("s_waitcnt vmcnt(0)" ::: "memory");
            }
            __builtin_amdgcn_s_barrier();
            __builtin_amdgcn_sched_barrier(0);

            const ushort_t* As = smem[c][0];
            const ushort_t* Bs = smem[c][1];
            short8 av[2][4], bv[2][4];
#pragma unroll
            for (int kk = 0; kk < 2; ++kk) {
                int slot = kk * 4 + (lane >> 4);
#pragma unroll
                for (int m = 0; m < 4; ++m) {
                    int row = wm * 64 + m * 16 + (lane & 15);
                    av[kk][m] = *(const short8*)(As + row * 64 + ((slot ^ (row & 7)) << 3));
                }
#pragma unroll
                for (int n = 0; n < 4; ++n) {
                    int row = wn * 64 + n * 16 + (lane & 15);
                    bv[kk][n] = *(const short8*)(Bs + row * 64 + ((slot ^ (row & 7)) << 3));
                }
            }
            if (more) stage4(aimg(nkv, nsign, njjs, nh), smem[c ^ 1][1]);

            asm volatile("s_waitcnt lgkmcnt(0)" ::: "memory");
            __builtin_amdgcn_sched_barrier(0);

            __builtin_amdgcn_s_setprio(1);
            if (sign == 0) {                          // static: rem unrolled
#pragma unroll
                for (int kk = 0; kk < 2; ++kk)
#pragma unroll
                    for (int m = 0; m < 4; ++m)
#pragma unroll
                        for (int n = 0; n < 4; ++n)
                            accp[m][n] = __builtin_amdgcn_mfma_f32_16x16x32_bf16(av[kk][m], bv[kk][n], accp[m][n], 0, 0, 0);
            } else {
#pragma unroll
                for (int kk = 0; kk < 2; ++kk)
#pragma unroll
                    for (int m = 0; m < 4; ++m)
#pragma unroll
                        for (int n = 0; n < 4; ++n)
                            accm[m][n] = __builtin_amdgcn_mfma_f32_16x16x32_bf16(av[kk][m], bv[kk][n], accm[m][n], 0, 0, 0);
            }
            __builtin_amdgcn_s_setprio(0);
            __builtin_amdgcn_s_barrier();
        }
    }

    // epilogue: out = accp + D*accm; row = rb + r4 (rb even) -> sign = (-1)^r4
    float* dst = outz + ((size_t)zc * SEQ + (size_t)i1 * 128) * DDIM + et * 128;
#pragma unroll
    for (int m = 0; m < 4; ++m) {
        int rb = wm * 64 + m * 16 + ((lane >> 4) << 2);
#pragma unroll
        for (int n = 0; n < 4; ++n) {
            int cb = wn * 64 + n * 16 + (lane & 15);
#pragma unroll
            for (int r4 = 0; r4 < 4; ++r4) {
                float vm = accm[m][n][r4];
                float v = accp[m][n][r4] + ((r4 & 1) ? -vm : vm);
                dst[(size_t)(rb + r4) * DDIM + cb] = v;
            }
        }
    }
}

// sum only z-slices that were written for this row: zc <= srow>>8
__global__ void k_reduce(const float* __restrict__ outz, float* __restrict__ out, int n4) {
    int idx = blockIdx.x * blockDim.x + threadIdx.x;
    if (idx < n4) {
        int srow = idx / (DDIM / 4);
        int zmax = srow >> 8;
        if (zmax > NZC - 1) zmax = NZC - 1;
        float4 s = ((const float4*)outz)[idx];
        for (int z = 1; z <= zmax; ++z) {
            float4 t = ((const float4*)(outz + (size_t)z * SEQ * DDIM))[idx];
            s.x += t.x; s.y += t.y; s.z += t.z; s.w += t.w;
        }
        ((float4*)out)[idx] = s;
    }
}

extern "C" void kernel_launch(void* const* d_in, const int* in_sizes, int n_in,
                              void* d_out, int out_size, void* d_ws, size_t ws_size,
                              hipStream_t stream) {
    (void)in_sizes; (void)n_in;
    const float* x   = (const float*)d_in[0];
    const float* phi = (const float*)d_in[1];
    const float* Mp  = (const float*)d_in[2];
    const float* Mm  = (const float*)d_in[3];
    float* out = (float*)d_out;

    char* ws = (char*)d_ws;
    size_t off = 0;
    auto alloc = [&](size_t bytes) { size_t o = off; off += (bytes + 255) & ~(size_t)255; return o; };
    size_t o_xpk = alloc((size_t)16 * 12 * 8192 * 2);                // 3.0 MB
    size_t o_Mpk = alloc((size_t)NKV * 6 * 12 * 8192 * 2);           // 56.6 MB (aliased by outz)
    size_t o_Tpk = alloc((size_t)KF * 17 * 2 * 8192 * 2);            // 13.4 MB (plus-only)
    size_t o_Apk = alloc((size_t)NKV * 6 * 16 * 2 * 8192 * 2);       // 151.0 MB
    if (off > ws_size) {   // should never happen (~224 MB total; prior rounds proved fits)
        hipMemsetAsync(d_out, 0, (size_t)out_size * 4, stream);
        return;
    }

    ushort_t* xpk = (ushort_t*)(ws + o_xpk);
    ushort_t* Mpk = (ushort_t*)(ws + o_Mpk);
    ushort_t* Tpk = (ushort_t*)(ws + o_Tpk);
    ushort_t* Apk = (ushort_t*)(ws + o_Apk);
    float*   outz = (float*)(ws + o_Mpk);   // alias: Mpk dead after gemm_A; 50.3 <= 56.6 MB

    k_prep<<<192 + 3456 + KF * 17, 256, 0, stream>>>(x, Mp, Mm, phi, xpk, Mpk, Tpk);
    k_gemm_A<<<NKV * 96, 256, 0, stream>>>(Mpk, xpk, Apk);
    k_gemm_Bv6<<<432, 256, 0, stream>>>(Tpk, Apk, outz);
    int n4 = SEQ * DDIM / 4;
    k_reduce<<<(n4 + 255) / 256, 256, 0, stream>>>(outz, out, n4);
}